// Round 1
// baseline (423944.043 us; speedup 1.0000x reference)
//
#include <hip/hip_runtime.h>
#include <hip/hip_cooperative_groups.h>
#include <cstdint>
#include <cstddef>

namespace cg = cooperative_groups;

// ---------------- problem constants ----------------
constexpr int B_     = 32;
constexpr int T_ENC  = 256;
constexpr int E_     = 512;
constexpr int A_RNN  = 1024;
constexpr int P_     = 256;
constexpr int N_MEL  = 80;
constexpr int TDEC   = 800;
constexpr int A_DIM  = 128;
constexpr int N_FILT = 32;
constexpr int KCONV  = 31;

// ---------------- workspace layout (floats) ----------------
constexpr int AH_OFF   = 0;               // 2 * 32*1024 (double-buffered)
constexpr int AC_OFF   = 65536;           // 32*1024
constexpr int DH_OFF   = 98304;           // 2 * 32*1024
constexpr int DC_OFF   = 163840;          // 32*1024
constexpr int CTX_OFF  = 196608;          // 2 * 32*512
constexpr int AW_OFF   = 229376;          // 32*256
constexpr int AWC_OFF  = 237568;          // 32*256
constexpr int EE_OFF   = 245760;          // 32*256
constexpr int STATE_FLOATS = 253952;      // memset region
constexpr int PRE_OFF  = 253952;          // 800*32*256
constexpr int PMEM_OFF = 6807552;         // 32*256*128
constexpr int W1T_OFF  = 7856128;         // 80*256
constexpr int W2T_OFF  = 7876608;         // 256*256

// ---------------- JAX threefry2x32 (exact) ----------------
__host__ __device__ inline void tf2x32(uint32_t k0, uint32_t k1, uint32_t& x0, uint32_t& x1) {
  const uint32_t ks2 = k0 ^ k1 ^ 0x1BD11BDAu;
  uint32_t y0 = x0 + k0, y1 = x1 + k1;
#define TFR(r) { y0 += y1; y1 = (y1 << (r)) | (y1 >> (32 - (r))); y1 ^= y0; }
  TFR(13) TFR(15) TFR(26) TFR(6)   y0 += k1;  y1 += ks2 + 1u;
  TFR(17) TFR(29) TFR(16) TFR(24)  y0 += ks2; y1 += k0 + 2u;
  TFR(13) TFR(15) TFR(26) TFR(6)   y0 += k0;  y1 += k1 + 3u;
  TFR(17) TFR(29) TFR(16) TFR(24)  y0 += k1;  y1 += ks2 + 4u;
  TFR(13) TFR(15) TFR(26) TFR(6)   y0 += ks2; y1 += k0 + 5u;
#undef TFR
  x0 = y0; x1 = y1;
}

// keep mask element i (partitionable scheme: bits = x0^x1 of tf(key,(0,i)); keep iff u<0.5 iff bit31==0)
__device__ inline bool tf_keep(uint32_t ka, uint32_t kb, uint32_t i) {
  uint32_t x0 = 0u, x1 = i;
  tf2x32(ka, kb, x0, x1);
  return (((x0 ^ x1) >> 31) == 0u);
}

__device__ inline float sigm(float x) { return 1.f / (1.f + expf(-x)); }

// ---------------- precompute kernels ----------------
__global__ __launch_bounds__(256) void transpose_k(const float* __restrict__ src,
                                                   float* __restrict__ dst, int R, int C) {
  int i = blockIdx.x * 256 + threadIdx.x;
  if (i < R * C) { int r = i / C, c = i % C; dst[c * R + r] = src[i]; }
}

// h1 = dropout(relu(x @ w1T)) ; x[t,b,m] = (t==0)?0:dec_in[b,m,t-1] ; one block per t
__global__ __launch_bounds__(256) void prenet1_kernel(const float* __restrict__ decin,
                                                      const float* __restrict__ w1T,
                                                      float* __restrict__ pre,
                                                      uint32_t ka, uint32_t kb) {
  __shared__ float xs[32][81];
  const int t = blockIdx.x, tid = threadIdx.x;
  for (int f = tid; f < 32 * 80; f += 256) {
    int b = f / 80, m = f % 80;
    xs[b][m] = (t == 0) ? 0.f : decin[b * 64000 + m * 800 + (t - 1)];
  }
  __syncthreads();
  const int p = tid;
  float acc[32];
#pragma unroll
  for (int r = 0; r < 32; ++r) acc[r] = 0.f;
  for (int m = 0; m < 80; ++m) {
    float wv = w1T[m * 256 + p];
#pragma unroll
    for (int r = 0; r < 32; ++r) acc[r] += xs[r][m] * wv;
  }
  float* rowbase = pre + (size_t)t * 32 * 256;
#pragma unroll
  for (int r = 0; r < 32; ++r) {
    float v = fmaxf(acc[r], 0.f);
    uint32_t i = (uint32_t)((t * 32 + r) * 256 + p);
    rowbase[r * 256 + p] = tf_keep(ka, kb, i) ? v * 2.f : 0.f;
  }
}

// pre = dropout(relu(h1 @ w2T)), in-place on pre rows; one block per t
__global__ __launch_bounds__(256) void prenet2_kernel(const float* __restrict__ w2T,
                                                      float* __restrict__ pre,
                                                      uint32_t ka, uint32_t kb) {
  __shared__ float hs[32][257];
  const int t = blockIdx.x, tid = threadIdx.x;
  float* rowbase = pre + (size_t)t * 32 * 256;
  for (int f = tid; f < 32 * 256; f += 256) {
    int b = f >> 8, k = f & 255;
    hs[b][k] = rowbase[b * 256 + k];
  }
  __syncthreads();
  const int p = tid;
  float acc[32];
#pragma unroll
  for (int r = 0; r < 32; ++r) acc[r] = 0.f;
  for (int k = 0; k < 256; ++k) {
    float wv = w2T[k * 256 + p];
#pragma unroll
    for (int r = 0; r < 32; ++r) acc[r] += hs[r][k] * wv;
  }
#pragma unroll
  for (int r = 0; r < 32; ++r) {
    float v = fmaxf(acc[r], 0.f);
    uint32_t i = (uint32_t)((t * 32 + r) * 256 + p);
    rowbase[r * 256 + p] = tf_keep(ka, kb, i) ? v * 2.f : 0.f;
  }
}

// pmem[b,t,a] = sum_e enc[b,t,e] * memW[e,a] ; block = (b, 8-row group), 128 threads
__global__ __launch_bounds__(128) void pmem_kernel(const float* __restrict__ enc,
                                                   const float* __restrict__ memW,
                                                   float* __restrict__ pmem) {
  __shared__ float es[8][513];
  const int b = blockIdx.x >> 5, tg = blockIdx.x & 31, t0 = tg * 8;
  const int tid = threadIdx.x;
  for (int f = tid; f < 8 * 512; f += 128) {
    int rr = f >> 9, e = f & 511;
    es[rr][e] = enc[(size_t)(b * 256 + t0 + rr) * 512 + e];
  }
  __syncthreads();
  float acc[8];
#pragma unroll
  for (int r = 0; r < 8; ++r) acc[r] = 0.f;
  const int a = tid;
  for (int e = 0; e < 512; ++e) {
    float wv = memW[e * 128 + a];
#pragma unroll
    for (int r = 0; r < 8; ++r) acc[r] += es[r][e] * wv;
  }
#pragma unroll
  for (int r = 0; r < 8; ++r) pmem[(size_t)(b * 256 + t0 + r) * 128 + a] = acc[r];
}

// ---------------- scan (cooperative) ----------------
struct ScanParams {
  const float* enc; const int* lens;
  const float* aWih; const float* aWhh; const float* abih; const float* abhh;
  const float* qW;   const float* vw;   const float* locW; const float* linW;
  const float* dWih; const float* dWhh; const float* dbih; const float* dbhh;
  const float* pW;   const float* pb;   const float* gW;   const float* gb;
  float* ah; float* ac; float* dh; float* dc; float* ctx; float* aw; float* awc; float* e;
  const float* pre; const float* pmem;
  float* mel_out; float* gate_out; float* align_out;
};

constexpr int SMEM_F = 32 * 132 + 512;  // 4736 floats (max over stages)

// acc += X[b][k0..] . Wrow[k0..] over len (len % 128 == 0), staging X chunks in LDS
__device__ __forceinline__ void gemm_seg(float4& accv, const float* __restrict__ X, int ldx,
                                         const float* __restrict__ wrow, int len,
                                         int b, int tid, float* xin_s) {
  for (int k0 = 0; k0 < len; k0 += 128) {
    for (int f = tid; f < 32 * 128; f += 512) {
      int bb = f >> 7, kk = f & 127;
      xin_s[bb * 132 + kk] = X[bb * ldx + k0 + kk];
    }
    __syncthreads();
    const float4* w4p = reinterpret_cast<const float4*>(wrow + k0);
    const float4* xr  = reinterpret_cast<const float4*>(xin_s + b * 132);
#pragma unroll
    for (int q = 0; q < 32; ++q) {
      float4 w4 = w4p[q];
      float4 x4 = xr[q];
      accv.x += w4.x * x4.x; accv.y += w4.y * x4.y;
      accv.z += w4.z * x4.z; accv.w += w4.w * x4.w;
    }
    __syncthreads();
  }
}

// one LSTM cell stage; block owns h-tile of 4, all 32 b, all 4 gates (512 outputs)
__device__ void lstm_stage(int blk, int tid,
                           const float* X0, int ld0, int len0,
                           const float* X1, int ld1, int len1,
                           const float* H,
                           const float* Wih, int ldWih, const float* Whh,
                           const float* bih, const float* bhh,
                           float* hout, float* cst, float* smem) {
  const int g = tid >> 7, hh = (tid >> 5) & 3, b = tid & 31;
  const int h0 = blk << 2;
  const int j = (g << 10) + h0 + hh;
  float4 accv = make_float4(0.f, 0.f, 0.f, 0.f);
  float* xin_s = smem;
  gemm_seg(accv, X0, ld0, Wih + (size_t)j * ldWih, len0, b, tid, xin_s);
  gemm_seg(accv, X1, ld1, Wih + (size_t)j * ldWih + len0, len1, b, tid, xin_s);
  gemm_seg(accv, H, 1024, Whh + (size_t)j * 1024, 1024, b, tid, xin_s);
  float acc = ((accv.x + accv.y) + (accv.z + accv.w)) + bih[j] + bhh[j];
  float* gate_s = smem + 32 * 132;
  gate_s[tid] = acc;
  __syncthreads();
  if (tid < 128) {
    const int hh2 = tid >> 5, b2 = tid & 31;
    const float gi = gate_s[(0 * 4 + hh2) * 32 + b2];
    const float gf = gate_s[(1 * 4 + hh2) * 32 + b2];
    const float gg = gate_s[(2 * 4 + hh2) * 32 + b2];
    const float go = gate_s[(3 * 4 + hh2) * 32 + b2];
    const int idx = (b2 << 10) + h0 + hh2;
    float c0 = cst[idx];
    float c = sigm(gf) * c0 + sigm(gi) * tanhf(gg);
    cst[idx] = c;
    hout[idx] = sigm(go) * tanhf(c);
  }
  __syncthreads();
}

// energies for (b = blk>>3, tt-tile of 32 = blk&7)
__device__ void stage_energies(int blk, int tid, const ScanParams& P, const float* ah_cur,
                               float* smem) {
  const int b = blk >> 3, tile = blk & 7, tt0 = tile * 32;
  float* part = smem;          // 512
  float* q_s  = smem + 512;    // 128
  float* sLoc = smem + 640;    // 2*64
  float* lf_s = smem + 768;    // 32*33
  float* vw_s = smem + 1824;   // 128
  {
    const int js = tid >> 7, a = tid & 127;
    float p = 0.f;
    const float* ahb = ah_cur + b * 1024 + js * 256;
    const float* qWb = P.qW + (js * 256) * 128 + a;
#pragma unroll 4
    for (int jj = 0; jj < 256; ++jj) p += ahb[jj] * qWb[jj * 128];
    part[tid] = p;
  }
  if (tid < 128) vw_s[tid] = P.vw[tid];
  __syncthreads();
  if (tid < 128) q_s[tid] = part[tid] + part[128 + tid] + part[256 + tid] + part[384 + tid];
  else if (tid < 256) {
    int u = tid - 128, c = u >> 6, uu = u & 63;
    int idx = tt0 - 15 + uu;
    float v = 0.f;
    if (idx >= 0 && idx < 256)
      v = (c == 0) ? P.aw[b * 256 + idx] : P.awc[b * 256 + idx];
    sLoc[c * 64 + uu] = v;
  }
  __syncthreads();
  // conv: 32 filt x 32 tt outputs, 2 per thread
#pragma unroll
  for (int oo = 0; oo < 2; ++oo) {
    int o = tid + oo * 512;
    int f = o >> 5, ttl = o & 31;
    float acc = 0.f;
#pragma unroll
    for (int c = 0; c < 2; ++c)
#pragma unroll
      for (int k = 0; k < KCONV; ++k)
        acc += sLoc[c * 64 + ttl + k] * P.locW[f * 62 + c * 31 + k];
    lf_s[f * 33 + ttl] = acc;
  }
  __syncthreads();
  // energies: thread = (ttl = tid>>4, s = tid&15), a = r*16+s
  const int ttl = tid >> 4, s = tid & 15;
  const int tt = tt0 + ttl;
  const int lb = P.lens[b];
  float esum = 0.f;
  const float* pmrow = P.pmem + (size_t)(b * 256 + tt) * 128;
#pragma unroll
  for (int r = 0; r < 8; ++r) {
    int a = r * 16 + s;
    float lfa = 0.f;
#pragma unroll
    for (int f = 0; f < 32; ++f) lfa += lf_s[f * 33 + ttl] * P.linW[f * 128 + a];
    float val = tanhf(q_s[a] + lfa + pmrow[a]);
    esum += val * vw_s[a];
  }
#pragma unroll
  for (int m = 1; m < 16; m <<= 1) esum += __shfl_xor(esum, m);
  if (s == 0) P.e[b * 256 + tt] = (tt < lb) ? esum : -1e9f;
}

__device__ void stage_softmax_ctx(int b, int tid, int t, const ScanParams& P,
                                  float* ctxp, float* smem) {
  float* es   = smem;        // 256
  float* redm = smem + 256;  // 8
  float* reds = smem + 264;  // 8
  float ev = (tid < 256) ? P.e[b * 256 + tid] : -3.0e38f;
  float v = ev;
#pragma unroll
  for (int m = 32; m >= 1; m >>= 1) v = fmaxf(v, __shfl_xor(v, m));
  if ((tid & 63) == 0) redm[tid >> 6] = v;
  __syncthreads();
  float mx = redm[0];
#pragma unroll
  for (int i = 1; i < 8; ++i) mx = fmaxf(mx, redm[i]);
  float p = 0.f;
  if (tid < 256) p = expf(ev - mx);
  float sv = p;
#pragma unroll
  for (int m = 32; m >= 1; m >>= 1) sv += __shfl_xor(sv, m);
  if ((tid & 63) == 0) reds[tid >> 6] = sv;
  __syncthreads();
  float denom = reds[0];
#pragma unroll
  for (int i = 1; i < 8; ++i) denom += reds[i];
  const float inv = 1.f / denom;
  if (tid < 256) {
    float awv = p * inv;
    es[tid] = awv;
    P.aw[b * 256 + tid] = awv;
    P.awc[b * 256 + tid] += awv;
    P.align_out[(size_t)b * 204800 + t * 256 + tid] = awv;
  }
  __syncthreads();
  float acc = 0.f;
  const float* encb = P.enc + (size_t)b * 131072 + tid;
#pragma unroll 4
  for (int tt = 0; tt < 256; ++tt) acc += es[tt] * encb[(size_t)tt * 512];
  ctxp[(b << 9) + tid] = acc;
}

__device__ void stage_proj(int b, int tid, int tp, const ScanParams& P,
                           const float* dh_prev, const float* ctx_prev, float* smem) {
  float* hc    = smem;         // 1536
  float* partm = smem + 1536;  // 6*80
  float* partg = smem + 2016;  // 32
  for (int i = tid; i < 1024; i += 512) hc[i] = dh_prev[b * 1024 + i];
  if (tid < 512) hc[1024 + tid] = ctx_prev[(b << 9) + tid];
  __syncthreads();
  if (tid < 480) {
    int ks = tid / 80, m = tid % 80;
    float acc = 0.f;
    const float* pWk = P.pW + (ks * 256) * 80 + m;
    const float* hck = hc + ks * 256;
#pragma unroll 4
    for (int k = 0; k < 256; ++k) acc += hck[k] * pWk[k * 80];
    partm[ks * 80 + m] = acc;
  } else {
    int s = tid - 480;
    float acc = 0.f;
    for (int k = s * 48; k < s * 48 + 48; ++k) acc += hc[k] * P.gW[k];
    partg[s] = acc;
  }
  __syncthreads();
  if (tid < 80) {
    float acc = P.pb[tid];
#pragma unroll
    for (int s = 0; s < 6; ++s) acc += partm[s * 80 + tid];
    P.mel_out[b * 64000 + tid * 800 + tp] = acc;
  }
  if (tid == 511) {
    float acc = P.gb[0];
#pragma unroll
    for (int s = 0; s < 32; ++s) acc += partg[s];
    P.gate_out[b * 800 + tp] = acc;
  }
  __syncthreads();
}

__global__ void __launch_bounds__(512) scan_kernel(ScanParams P) {
  cg::grid_group grid = cg::this_grid();
  const int blk = blockIdx.x, tid = threadIdx.x;
  __shared__ float smem[SMEM_F];

  for (int t = 0; t < TDEC; ++t) {
    const int wp = t & 1, rp = wp ^ 1;
    // S1: attention LSTM
    lstm_stage(blk, tid,
               P.pre + (size_t)t * 8192, 256, 256,
               P.ctx + rp * 16384, 512, 512,
               P.ah + rp * 32768,
               P.aWih, 768, P.aWhh, P.abih, P.abhh,
               P.ah + wp * 32768, P.ac, smem);
    grid.sync();
    // S2: attention energies
    stage_energies(blk, tid, P, P.ah + wp * 32768, smem);
    grid.sync();
    // S3: softmax+context (blocks 0..31) || projection of step t-1 (blocks 32..63)
    if (blk < 32)
      stage_softmax_ctx(blk, tid, t, P, P.ctx + wp * 16384, smem);
    else if (blk < 64 && t > 0)
      stage_proj(blk - 32, tid, t - 1, P, P.dh + rp * 32768, P.ctx + rp * 16384, smem);
    grid.sync();
    // S4: decoder LSTM
    lstm_stage(blk, tid,
               P.ah + wp * 32768, 1024, 1024,
               P.ctx + wp * 16384, 512, 512,
               P.dh + rp * 32768,
               P.dWih, 1536, P.dWhh, P.dbih, P.dbhh,
               P.dh + wp * 32768, P.dc, smem);
    grid.sync();
  }
  // final projection for t = 799 (last write parity wp = 1)
  if (blk >= 32 && blk < 64)
    stage_proj(blk - 32, tid, 799, P, P.dh + 32768, P.ctx + 16384, smem);
}

// ---------------- host launch ----------------
extern "C" void kernel_launch(void* const* d_in, const int* in_sizes, int n_in,
                              void* d_out, int out_size, void* d_ws, size_t ws_size,
                              hipStream_t stream) {
  (void)in_sizes; (void)n_in; (void)out_size; (void)ws_size;
  const float* enc   = (const float*)d_in[0];
  const float* decin = (const float*)d_in[1];
  const int*   lens  = (const int*)d_in[2];
  const float* w1    = (const float*)d_in[3];
  const float* w2    = (const float*)d_in[4];
  const float* aWih  = (const float*)d_in[5];
  const float* aWhh  = (const float*)d_in[6];
  const float* abih  = (const float*)d_in[7];
  const float* abhh  = (const float*)d_in[8];
  const float* qW    = (const float*)d_in[9];
  const float* memW  = (const float*)d_in[10];
  const float* vw    = (const float*)d_in[11];
  const float* locW  = (const float*)d_in[12];
  const float* linW  = (const float*)d_in[13];
  const float* dWih  = (const float*)d_in[14];
  const float* dWhh  = (const float*)d_in[15];
  const float* dbih  = (const float*)d_in[16];
  const float* dbhh  = (const float*)d_in[17];
  const float* pW    = (const float*)d_in[18];
  const float* pb    = (const float*)d_in[19];
  const float* gW    = (const float*)d_in[20];
  const float* gb    = (const float*)d_in[21];

  float* ws  = (float*)d_ws;
  float* out = (float*)d_out;

  // re-zero recurrent state every call (graph replays must be identical)
  hipMemsetAsync(ws, 0, (size_t)STATE_FLOATS * sizeof(float), stream);

  // JAX key(42) -> split (foldlike / partitionable): k_i = threefry(key, (0, i))
  uint32_t k1a, k1b, k2a, k2b;
  { uint32_t a = 0u, b = 0u; tf2x32(0u, 42u, a, b); k1a = a; k1b = b; }
  { uint32_t a = 0u, b = 1u; tf2x32(0u, 42u, a, b); k2a = a; k2b = b; }

  transpose_k<<<dim3((256 * 80 + 255) / 256), dim3(256), 0, stream>>>(w1, ws + W1T_OFF, 256, 80);
  transpose_k<<<dim3((256 * 256 + 255) / 256), dim3(256), 0, stream>>>(w2, ws + W2T_OFF, 256, 256);
  prenet1_kernel<<<dim3(800), dim3(256), 0, stream>>>(decin, ws + W1T_OFF, ws + PRE_OFF, k1a, k1b);
  prenet2_kernel<<<dim3(800), dim3(256), 0, stream>>>(ws + W2T_OFF, ws + PRE_OFF, k2a, k2b);
  pmem_kernel<<<dim3(1024), dim3(128), 0, stream>>>(enc, memW, ws + PMEM_OFF);

  ScanParams prm;
  prm.enc = enc; prm.lens = lens;
  prm.aWih = aWih; prm.aWhh = aWhh; prm.abih = abih; prm.abhh = abhh;
  prm.qW = qW; prm.vw = vw; prm.locW = locW; prm.linW = linW;
  prm.dWih = dWih; prm.dWhh = dWhh; prm.dbih = dbih; prm.dbhh = dbhh;
  prm.pW = pW; prm.pb = pb; prm.gW = gW; prm.gb = gb;
  prm.ah = ws + AH_OFF; prm.ac = ws + AC_OFF;
  prm.dh = ws + DH_OFF; prm.dc = ws + DC_OFF;
  prm.ctx = ws + CTX_OFF; prm.aw = ws + AW_OFF; prm.awc = ws + AWC_OFF; prm.e = ws + EE_OFF;
  prm.pre = ws + PRE_OFF; prm.pmem = ws + PMEM_OFF;
  prm.mel_out = out; prm.gate_out = out + 2048000; prm.align_out = out + 2073600;

  void* kargs[] = { (void*)&prm };
  hipLaunchCooperativeKernel(scan_kernel, dim3(256), dim3(512), kargs, 0, stream);
}

// Round 2
// 360510.669 us; speedup vs baseline: 1.1760x; 1.1760x over previous
//
#include <hip/hip_runtime.h>
#include <hip/hip_cooperative_groups.h>
#include <cstdint>
#include <cstddef>

namespace cg = cooperative_groups;

// ---------------- problem constants ----------------
constexpr int TDEC   = 800;
constexpr int KCONV  = 31;

// ---------------- workspace layout (floats) ----------------
constexpr int AH_OFF   = 0;               // 2 * 32*1024 (double-buffered)
constexpr int AC_OFF   = 65536;           // 32*1024
constexpr int DH_OFF   = 98304;           // 2 * 32*1024
constexpr int DC_OFF   = 163840;          // 32*1024
constexpr int CTX_OFF  = 196608;          // 2 * 32*512
constexpr int AW_OFF   = 229376;          // 32*256
constexpr int AWC_OFF  = 237568;          // 32*256
constexpr int EE_OFF   = 245760;          // 32*256 (unused now)
constexpr int STATE_FLOATS = 253952;      // memset region
constexpr int PRE_OFF  = 253952;          // 800*32*256
constexpr int PMEM_OFF = 6807552;         // 32*256*128
constexpr int W1T_OFF  = 7856128;         // 80*256
constexpr int W2T_OFF  = 7876608;         // 256*256
constexpr int LINT_OFF = 7942144;         // 128*32

// ---------------- JAX threefry2x32 (exact) ----------------
__host__ __device__ inline void tf2x32(uint32_t k0, uint32_t k1, uint32_t& x0, uint32_t& x1) {
  const uint32_t ks2 = k0 ^ k1 ^ 0x1BD11BDAu;
  uint32_t y0 = x0 + k0, y1 = x1 + k1;
#define TFR(r) { y0 += y1; y1 = (y1 << (r)) | (y1 >> (32 - (r))); y1 ^= y0; }
  TFR(13) TFR(15) TFR(26) TFR(6)   y0 += k1;  y1 += ks2 + 1u;
  TFR(17) TFR(29) TFR(16) TFR(24)  y0 += ks2; y1 += k0 + 2u;
  TFR(13) TFR(15) TFR(26) TFR(6)   y0 += k0;  y1 += k1 + 3u;
  TFR(17) TFR(29) TFR(16) TFR(24)  y0 += k1;  y1 += ks2 + 4u;
  TFR(13) TFR(15) TFR(26) TFR(6)   y0 += ks2; y1 += k0 + 5u;
#undef TFR
  x0 = y0; x1 = y1;
}

__device__ inline bool tf_keep(uint32_t ka, uint32_t kb, uint32_t i) {
  uint32_t x0 = 0u, x1 = i;
  tf2x32(ka, kb, x0, x1);
  return (((x0 ^ x1) >> 31) == 0u);
}

__device__ inline float sigm(float x) { return 1.f / (1.f + expf(-x)); }

// ---------------- precompute kernels ----------------
__global__ __launch_bounds__(256) void transpose_k(const float* __restrict__ src,
                                                   float* __restrict__ dst, int R, int C) {
  int i = blockIdx.x * 256 + threadIdx.x;
  if (i < R * C) { int r = i / C, c = i % C; dst[c * R + r] = src[i]; }
}

__global__ __launch_bounds__(256) void prenet1_kernel(const float* __restrict__ decin,
                                                      const float* __restrict__ w1T,
                                                      float* __restrict__ pre,
                                                      uint32_t ka, uint32_t kb) {
  __shared__ float xs[32][81];
  const int t = blockIdx.x, tid = threadIdx.x;
  for (int f = tid; f < 32 * 80; f += 256) {
    int b = f / 80, m = f % 80;
    xs[b][m] = (t == 0) ? 0.f : decin[b * 64000 + m * 800 + (t - 1)];
  }
  __syncthreads();
  const int p = tid;
  float acc[32];
#pragma unroll
  for (int r = 0; r < 32; ++r) acc[r] = 0.f;
  for (int m = 0; m < 80; ++m) {
    float wv = w1T[m * 256 + p];
#pragma unroll
    for (int r = 0; r < 32; ++r) acc[r] += xs[r][m] * wv;
  }
  float* rowbase = pre + (size_t)t * 32 * 256;
#pragma unroll
  for (int r = 0; r < 32; ++r) {
    float v = fmaxf(acc[r], 0.f);
    uint32_t i = (uint32_t)((t * 32 + r) * 256 + p);
    rowbase[r * 256 + p] = tf_keep(ka, kb, i) ? v * 2.f : 0.f;
  }
}

__global__ __launch_bounds__(256) void prenet2_kernel(const float* __restrict__ w2T,
                                                      float* __restrict__ pre,
                                                      uint32_t ka, uint32_t kb) {
  __shared__ float hs[32][257];
  const int t = blockIdx.x, tid = threadIdx.x;
  float* rowbase = pre + (size_t)t * 32 * 256;
  for (int f = tid; f < 32 * 256; f += 256) {
    int b = f >> 8, k = f & 255;
    hs[b][k] = rowbase[b * 256 + k];
  }
  __syncthreads();
  const int p = tid;
  float acc[32];
#pragma unroll
  for (int r = 0; r < 32; ++r) acc[r] = 0.f;
  for (int k = 0; k < 256; ++k) {
    float wv = w2T[k * 256 + p];
#pragma unroll
    for (int r = 0; r < 32; ++r) acc[r] += hs[r][k] * wv;
  }
#pragma unroll
  for (int r = 0; r < 32; ++r) {
    float v = fmaxf(acc[r], 0.f);
    uint32_t i = (uint32_t)((t * 32 + r) * 256 + p);
    rowbase[r * 256 + p] = tf_keep(ka, kb, i) ? v * 2.f : 0.f;
  }
}

__global__ __launch_bounds__(128) void pmem_kernel(const float* __restrict__ enc,
                                                   const float* __restrict__ memW,
                                                   float* __restrict__ pmem) {
  __shared__ float es[8][513];
  const int b = blockIdx.x >> 5, tg = blockIdx.x & 31, t0 = tg * 8;
  const int tid = threadIdx.x;
  for (int f = tid; f < 8 * 512; f += 128) {
    int rr = f >> 9, e = f & 511;
    es[rr][e] = enc[(size_t)(b * 256 + t0 + rr) * 512 + e];
  }
  __syncthreads();
  float acc[8];
#pragma unroll
  for (int r = 0; r < 8; ++r) acc[r] = 0.f;
  const int a = tid;
  for (int e = 0; e < 512; ++e) {
    float wv = memW[e * 128 + a];
#pragma unroll
    for (int r = 0; r < 8; ++r) acc[r] += es[r][e] * wv;
  }
#pragma unroll
  for (int r = 0; r < 8; ++r) pmem[(size_t)(b * 256 + t0 + r) * 128 + a] = acc[r];
}

// ---------------- scan (cooperative) ----------------
struct ScanParams {
  const float* enc; const int* lens;
  const float* aWih; const float* aWhh; const float* abih; const float* abhh;
  const float* qW;   const float* vw;   const float* locW; const float* linT;
  const float* dWih; const float* dWhh; const float* dbih; const float* dbhh;
  const float* pW;   const float* pb;   const float* gW;   const float* gb;
  float* ah; float* ac; float* dh; float* dc; float* ctx; float* aw; float* awc;
  const float* pre; const float* pmem;
  float* mel_out; float* gate_out; float* align_out;
};

constexpr int SMEM_F = 11456;   // max over stages (S2 layout); LSTM uses 8720

struct XW { const float* x; int ldx; const float* w; int ldw; };

__device__ __forceinline__ void stage_load(const XW& ch, float4* sreg, int tid) {
#pragma unroll
  for (int u = 0; u < 2; ++u) {
    int f4 = tid * 2 + u;
    int bs = f4 >> 6;
    int kk = (f4 & 63) * 4;
    sreg[u] = *(const float4*)(ch.x + (size_t)bs * ch.ldx + kk);
  }
}
__device__ __forceinline__ void stage_store(const float4* sreg, float* dst, int tid) {
#pragma unroll
  for (int u = 0; u < 2; ++u) {
    int f4 = tid * 2 + u;
    int bs = f4 >> 6;
    int kk = (f4 & 63) * 4;
    *(float4*)(dst + bs * 256 + kk) = sreg[u];
  }
}

// block: 1024 threads = jg(4 gates) x bg(4) x lane(64).  Per-thread tile: 4 rows x 8 b.
// Each wave-load of weights = 64 lanes x float4 = 1 KB contiguous unique bytes.
template <typename F>
__device__ __forceinline__ void lstm_core(int blk, int tid, int nc, F getc,
                                          const float* bih, const float* bhh,
                                          float* hout, float* cst, float* smem) {
  const int lane = tid & 63;
  const int bg = (tid >> 6) & 3;
  const int jg = tid >> 8;            // == gate index 0..3 (i,f,g,o)
  const int b0 = bg * 8;
  const int hb = blk * 4;
  float* xs = smem;                   // [32][256]
  float* gate_s = smem + 8192;        // [16][33]

  float acc[4][8];
#pragma unroll
  for (int rr = 0; rr < 4; ++rr) {
    float bv = (lane == 0) ? (bih[jg * 1024 + hb + rr] + bhh[jg * 1024 + hb + rr]) : 0.f;
#pragma unroll
    for (int bb = 0; bb < 8; ++bb) acc[rr][bb] = bv;
  }

  // prologue: stage chunk 0, prefetch its weights
  float4 sreg[2];
  {
    XW c0 = getc(0);
    stage_load(c0, sreg, tid);
    stage_store(sreg, xs, tid);
  }
  float4 wc[4];
  {
    XW c0 = getc(0);
#pragma unroll
    for (int rr = 0; rr < 4; ++rr)
      wc[rr] = *(const float4*)(c0.w + (size_t)(jg * 1024 + hb + rr) * c0.ldw + lane * 4);
  }
  __syncthreads();

  for (int c = 0; c < nc; ++c) {
    float4 wn[4];
    const bool more = (c + 1 < nc);
    if (more) {
      XW cn = getc(c + 1);
      stage_load(cn, sreg, tid);          // global->regs, hidden under FMAs
#pragma unroll
      for (int rr = 0; rr < 4; ++rr)
        wn[rr] = *(const float4*)(cn.w + (size_t)(jg * 1024 + hb + rr) * cn.ldw + lane * 4);
    }
#pragma unroll
    for (int bb = 0; bb < 8; ++bb) {
      float4 x4 = *(const float4*)(xs + (b0 + bb) * 256 + lane * 4);
#pragma unroll
      for (int rr = 0; rr < 4; ++rr) {
        acc[rr][bb] = fmaf(wc[rr].x, x4.x, acc[rr][bb]);
        acc[rr][bb] = fmaf(wc[rr].y, x4.y, acc[rr][bb]);
        acc[rr][bb] = fmaf(wc[rr].z, x4.z, acc[rr][bb]);
        acc[rr][bb] = fmaf(wc[rr].w, x4.w, acc[rr][bb]);
      }
    }
    __syncthreads();                       // everyone done reading xs
    if (more) {
      stage_store(sreg, xs, tid);          // regs->LDS
#pragma unroll
      for (int rr = 0; rr < 4; ++rr) wc[rr] = wn[rr];
      __syncthreads();                     // writes visible
    }
  }

  // reduce 32 partials across 64 lanes: halving butterfly; each sum lands on a lane
  float v[32];
#pragma unroll
  for (int rr = 0; rr < 4; ++rr)
#pragma unroll
    for (int bb = 0; bb < 8; ++bb) v[rr * 8 + bb] = acc[rr][bb];
#pragma unroll
  for (int s = 0; s < 5; ++s) {
    const int d = 32 >> s;
    const int half = 32 >> (s + 1);
    const bool up = (lane & d) != 0;
#pragma unroll
    for (int i = 0; i < 16; ++i) {
      if (i < half) {
        float send = up ? v[i] : v[i + half];
        float got = __shfl_xor(send, d);
        v[i] = (up ? v[i + half] : v[i]) + got;
      }
    }
  }
  v[0] += __shfl_xor(v[0], 1);
  if ((lane & 1) == 0) {
    int p = (lane >> 1) & 31;            // idx = 16*b5+8*b4+4*b3+2*b2+1*b1
    int rr = p >> 3, bb = p & 7;
    gate_s[(jg * 4 + rr) * 33 + (b0 + bb)] = v[0];
  }
  __syncthreads();
  if (tid < 128) {
    int hl = tid >> 5, b = tid & 31;
    float gi = gate_s[(0 + hl) * 33 + b];
    float gf = gate_s[(4 + hl) * 33 + b];
    float gg = gate_s[(8 + hl) * 33 + b];
    float go = gate_s[(12 + hl) * 33 + b];
    int idx = b * 1024 + hb + hl;
    float c0v = cst[idx];
    float cn = sigm(gf) * c0v + sigm(gi) * tanhf(gg);
    cst[idx] = cn;
    hout[idx] = sigm(go) * tanhf(cn);
  }
}

// fused attention for batch b: q, loc-conv, energies, softmax, ctx (one block per b)
__device__ void stage_attn(int b, int tid, int t, const ScanParams& P,
                           const float* ah_cur, float* ctx_out, float* smem) {
  float* part = smem;            // 1024 (reused: q-partials, energy partials, exp)
  float* sLoc = smem + 1024;     // 572
  float* q_s  = smem + 1600;     // 128
  float* vw_s = smem + 1728;     // 128
  float* red  = smem + 1856;     // 2
  float* aw_s = smem + 1888;     // 256
  float* cpart= smem + 2144;     // 1024
  float* lf_s = smem + 3200;     // 32*258
  // phase A: q partials + sLoc + vw
  {
    const int js = tid >> 7, a = tid & 127;
    const float* ahb = ah_cur + b * 1024 + js * 128;
    const float* qp = P.qW + (size_t)(js * 128) * 128 + a;
    float p0 = 0.f, p1 = 0.f, p2 = 0.f, p3 = 0.f;
    for (int j = 0; j < 128; j += 4) {
      p0 += ahb[j] * qp[(size_t)j * 128];
      p1 += ahb[j + 1] * qp[(size_t)(j + 1) * 128];
      p2 += ahb[j + 2] * qp[(size_t)(j + 2) * 128];
      p3 += ahb[j + 3] * qp[(size_t)(j + 3) * 128];
    }
    part[tid] = (p0 + p1) + (p2 + p3);
  }
  if (tid < 572) {
    int c = tid / 286, i = tid % 286;
    int src = i - 15;
    float vv = 0.f;
    if (src >= 0 && src < 256) vv = (c == 0 ? P.aw : P.awc)[b * 256 + src];
    sLoc[c * 286 + i] = vv;
  } else if (tid < 700) {
    vw_s[tid - 572] = P.vw[tid - 572];
  }
  __syncthreads();
  // phase B: q_s reduce + location conv -> lf_s[f][tt]
  if (tid < 128) {
    float q = 0.f;
#pragma unroll
    for (int js = 0; js < 8; ++js) q += part[js * 128 + tid];
    q_s[tid] = q;
  }
  {
    const int f = tid >> 5, tg = tid & 31;
    float accL[8];
#pragma unroll
    for (int i = 0; i < 8; ++i) accL[i] = 0.f;
    const float* wf = P.locW + f * 62;
#pragma unroll
    for (int c = 0; c < 2; ++c)
#pragma unroll
      for (int k = 0; k < KCONV; ++k) {
        float wv = wf[c * 31 + k];
        const float* sl = sLoc + c * 286 + tg * 8 + k;
#pragma unroll
        for (int i = 0; i < 8; ++i) accL[i] += sl[i] * wv;
      }
#pragma unroll
    for (int i = 0; i < 8; ++i) lf_s[f * 258 + tg * 8 + i] = accL[i];
  }
  __syncthreads();
  // phase C: energies, each thread = (tt, quarter of a-dim)
  {
    const int tt = tid >> 2, aq = tid & 3;
    float lfv[32];
#pragma unroll
    for (int f = 0; f < 32; ++f) lfv[f] = lf_s[f * 258 + tt];
    const float* pm = P.pmem + (size_t)(b * 256 + tt) * 128;
    float ep = 0.f;
#pragma unroll 4
    for (int ai = 0; ai < 32; ++ai) {
      int a = aq * 32 + ai;
      const float4* lt = (const float4*)(P.linT + a * 32);
      float lfa = 0.f;
#pragma unroll
      for (int u = 0; u < 8; ++u) {
        float4 l4 = lt[u];
        lfa += l4.x * lfv[u * 4] + l4.y * lfv[u * 4 + 1] + l4.z * lfv[u * 4 + 2] + l4.w * lfv[u * 4 + 3];
      }
      float val = tanhf(q_s[a] + lfa + pm[a]);
      ep += val * vw_s[a];
    }
    part[tid] = ep;   // part[tt*4+aq]
  }
  __syncthreads();
  // phase D: mask + softmax over 256
  const int len_b = P.lens[b];
  if (tid < 256) {
    float e = part[tid * 4] + part[tid * 4 + 1] + part[tid * 4 + 2] + part[tid * 4 + 3];
    e = (tid < len_b) ? e : -1e9f;
    aw_s[tid] = e;
  }
  __syncthreads();
  if (tid < 64) {
    float m0 = fmaxf(fmaxf(aw_s[tid], aw_s[64 + tid]), fmaxf(aw_s[128 + tid], aw_s[192 + tid]));
#pragma unroll
    for (int m = 32; m >= 1; m >>= 1) m0 = fmaxf(m0, __shfl_xor(m0, m));
    if (tid == 0) red[0] = m0;
  }
  __syncthreads();
  const float mx = red[0];
  if (tid < 256) part[tid] = expf(aw_s[tid] - mx);
  __syncthreads();
  if (tid < 64) {
    float s0 = part[tid] + part[64 + tid] + part[128 + tid] + part[192 + tid];
#pragma unroll
    for (int m = 32; m >= 1; m >>= 1) s0 += __shfl_xor(s0, m);
    if (tid == 0) red[1] = s0;
  }
  __syncthreads();
  const float inv = 1.f / red[1];
  if (tid < 256) {
    float awv = part[tid] * inv;
    aw_s[tid] = awv;
    P.aw[b * 256 + tid] = awv;
    P.awc[b * 256 + tid] += awv;
    P.align_out[(size_t)b * 204800 + (size_t)t * 256 + tid] = awv;
  }
  __syncthreads();
  // phase E: ctx = aw @ enc
  {
    const int ee = tid & 511, hf = tid >> 9;
    const float* encb = P.enc + (size_t)b * 131072 + (size_t)hf * 128 * 512 + ee;
    float a0 = 0.f, a1 = 0.f, a2 = 0.f, a3 = 0.f;
    for (int tt = 0; tt < 128; tt += 4) {
      a0 += aw_s[hf * 128 + tt] * encb[(size_t)tt * 512];
      a1 += aw_s[hf * 128 + tt + 1] * encb[(size_t)(tt + 1) * 512];
      a2 += aw_s[hf * 128 + tt + 2] * encb[(size_t)(tt + 2) * 512];
      a3 += aw_s[hf * 128 + tt + 3] * encb[(size_t)(tt + 3) * 512];
    }
    cpart[hf * 512 + ee] = (a0 + a1) + (a2 + a3);
  }
  __syncthreads();
  if (tid < 512) ctx_out[b * 512 + tid] = cpart[tid] + cpart[512 + tid];
}

__device__ void stage_proj(int b, int tid, int tp, const ScanParams& P,
                           const float* dh_prev, const float* ctx_prev, float* smem) {
  float* hc    = smem;         // 1536
  float* partm = smem + 1536;  // 480
  float* partg = smem + 2016;  // 32
  for (int i = tid; i < 1536; i += 1024)
    hc[i] = (i < 1024) ? dh_prev[b * 1024 + i] : ctx_prev[b * 512 + (i - 1024)];
  __syncthreads();
  if (tid < 480) {
    int ks = tid / 80, m = tid % 80;
    const float* pWk = P.pW + (size_t)(ks * 256) * 80 + m;
    const float* hck = hc + ks * 256;
    float a0 = 0.f, a1 = 0.f, a2 = 0.f, a3 = 0.f;
    for (int k = 0; k < 256; k += 4) {
      a0 += hck[k] * pWk[(size_t)k * 80];
      a1 += hck[k + 1] * pWk[(size_t)(k + 1) * 80];
      a2 += hck[k + 2] * pWk[(size_t)(k + 2) * 80];
      a3 += hck[k + 3] * pWk[(size_t)(k + 3) * 80];
    }
    partm[ks * 80 + m] = (a0 + a1) + (a2 + a3);
  } else if (tid < 512) {
    int s = tid - 480;
    float acc = 0.f;
    for (int k = s * 48; k < s * 48 + 48; ++k) acc += hc[k] * P.gW[k];
    partg[s] = acc;
  }
  __syncthreads();
  if (tid < 80) {
    float acc = P.pb[tid];
#pragma unroll
    for (int s = 0; s < 6; ++s) acc += partm[s * 80 + tid];
    P.mel_out[b * 64000 + tid * 800 + tp] = acc;
  }
  if (tid == 511) {
    float acc = P.gb[0];
#pragma unroll
    for (int s = 0; s < 32; ++s) acc += partg[s];
    P.gate_out[b * 800 + tp] = acc;
  }
}

__global__ void __launch_bounds__(1024, 4) scan_kernel(ScanParams P) {
  cg::grid_group grid = cg::this_grid();
  const int blk = blockIdx.x, tid = threadIdx.x;
  __shared__ float smem[SMEM_F];

  for (int t = 0; t < TDEC; ++t) {
    const int wp = t & 1, rp = wp ^ 1;
    // ---- S1: attention LSTM ----
    {
      const float* pre_t = P.pre + (size_t)t * 8192;
      const float* ctx_r = P.ctx + rp * 16384;
      const float* ah_r  = P.ah + rp * 32768;
      const ScanParams& Q = P;
      auto getc1 = [&](int c) -> XW {
        XW r;
        if (c == 0)      { r.x = pre_t;               r.ldx = 256;  r.w = Q.aWih;                      r.ldw = 768; }
        else if (c <= 2) { r.x = ctx_r + (c - 1) * 256; r.ldx = 512; r.w = Q.aWih + 256 + (c - 1) * 256; r.ldw = 768; }
        else             { r.x = ah_r + (c - 3) * 256;  r.ldx = 1024; r.w = Q.aWhh + (c - 3) * 256;      r.ldw = 1024; }
        return r;
      };
      lstm_core(blk, tid, 7, getc1, P.abih, P.abhh, P.ah + wp * 32768, P.ac, smem);
    }
    grid.sync();
    // ---- S2: attention (blocks 0..31) || projection t-1 (blocks 32..63) ----
    if (blk < 32)
      stage_attn(blk, tid, t, P, P.ah + wp * 32768, P.ctx + wp * 16384, smem);
    else if (blk < 64 && t > 0)
      stage_proj(blk - 32, tid, t - 1, P, P.dh + rp * 32768, P.ctx + rp * 16384, smem);
    grid.sync();
    // ---- S3: decoder LSTM ----
    {
      const float* ah_w  = P.ah + wp * 32768;
      const float* ctx_w = P.ctx + wp * 16384;
      const float* dh_r  = P.dh + rp * 32768;
      const ScanParams& Q = P;
      auto getc2 = [&](int c) -> XW {
        XW r;
        if (c <= 3)      { r.x = ah_w + c * 256;        r.ldx = 1024; r.w = Q.dWih + c * 256;            r.ldw = 1536; }
        else if (c <= 5) { r.x = ctx_w + (c - 4) * 256; r.ldx = 512;  r.w = Q.dWih + 1024 + (c - 4) * 256; r.ldw = 1536; }
        else             { r.x = dh_r + (c - 6) * 256;  r.ldx = 1024; r.w = Q.dWhh + (c - 6) * 256;       r.ldw = 1024; }
        return r;
      };
      lstm_core(blk, tid, 10, getc2, P.dbih, P.dbhh, P.dh + wp * 32768, P.dc, smem);
    }
    grid.sync();
  }
  if (blk >= 32 && blk < 64)
    stage_proj(blk - 32, tid, 799, P, P.dh + 32768, P.ctx + 16384, smem);
}

// ---------------- host launch ----------------
extern "C" void kernel_launch(void* const* d_in, const int* in_sizes, int n_in,
                              void* d_out, int out_size, void* d_ws, size_t ws_size,
                              hipStream_t stream) {
  (void)in_sizes; (void)n_in; (void)out_size; (void)ws_size;
  const float* enc   = (const float*)d_in[0];
  const float* decin = (const float*)d_in[1];
  const int*   lens  = (const int*)d_in[2];
  const float* w1    = (const float*)d_in[3];
  const float* w2    = (const float*)d_in[4];
  const float* aWih  = (const float*)d_in[5];
  const float* aWhh  = (const float*)d_in[6];
  const float* abih  = (const float*)d_in[7];
  const float* abhh  = (const float*)d_in[8];
  const float* qW    = (const float*)d_in[9];
  const float* memW  = (const float*)d_in[10];
  const float* vw    = (const float*)d_in[11];
  const float* locW  = (const float*)d_in[12];
  const float* linW  = (const float*)d_in[13];
  const float* dWih  = (const float*)d_in[14];
  const float* dWhh  = (const float*)d_in[15];
  const float* dbih  = (const float*)d_in[16];
  const float* dbhh  = (const float*)d_in[17];
  const float* pW    = (const float*)d_in[18];
  const float* pb    = (const float*)d_in[19];
  const float* gW    = (const float*)d_in[20];
  const float* gb    = (const float*)d_in[21];

  float* ws  = (float*)d_ws;
  float* out = (float*)d_out;

  hipMemsetAsync(ws, 0, (size_t)STATE_FLOATS * sizeof(float), stream);

  uint32_t k1a, k1b, k2a, k2b;
  { uint32_t a = 0u, b = 0u; tf2x32(0u, 42u, a, b); k1a = a; k1b = b; }
  { uint32_t a = 0u, b = 1u; tf2x32(0u, 42u, a, b); k2a = a; k2b = b; }

  transpose_k<<<dim3((256 * 80 + 255) / 256), dim3(256), 0, stream>>>(w1, ws + W1T_OFF, 256, 80);
  transpose_k<<<dim3((256 * 256 + 255) / 256), dim3(256), 0, stream>>>(w2, ws + W2T_OFF, 256, 256);
  transpose_k<<<dim3((32 * 128 + 255) / 256), dim3(256), 0, stream>>>(linW, ws + LINT_OFF, 32, 128);
  prenet1_kernel<<<dim3(800), dim3(256), 0, stream>>>(decin, ws + W1T_OFF, ws + PRE_OFF, k1a, k1b);
  prenet2_kernel<<<dim3(800), dim3(256), 0, stream>>>(ws + W2T_OFF, ws + PRE_OFF, k2a, k2b);
  pmem_kernel<<<dim3(1024), dim3(128), 0, stream>>>(enc, memW, ws + PMEM_OFF);

  ScanParams prm;
  prm.enc = enc; prm.lens = lens;
  prm.aWih = aWih; prm.aWhh = aWhh; prm.abih = abih; prm.abhh = abhh;
  prm.qW = qW; prm.vw = vw; prm.locW = locW; prm.linT = ws + LINT_OFF;
  prm.dWih = dWih; prm.dWhh = dWhh; prm.dbih = dbih; prm.dbhh = dbhh;
  prm.pW = pW; prm.pb = pb; prm.gW = gW; prm.gb = gb;
  prm.ah = ws + AH_OFF; prm.ac = ws + AC_OFF;
  prm.dh = ws + DH_OFF; prm.dc = ws + DC_OFF;
  prm.ctx = ws + CTX_OFF; prm.aw = ws + AW_OFF; prm.awc = ws + AWC_OFF;
  prm.pre = ws + PRE_OFF; prm.pmem = ws + PMEM_OFF;
  prm.mel_out = out; prm.gate_out = out + 2048000; prm.align_out = out + 2073600;

  void* kargs[] = { (void*)&prm };
  hipLaunchCooperativeKernel(scan_kernel, dim3(256), dim3(1024), kargs, 0, stream);
}